// Round 3
// baseline (489.444 us; speedup 1.0000x reference)
//
#include <hip/hip_runtime.h>

typedef unsigned int uint;
typedef unsigned short ushort;

#define NN 1000000
#define KSZ 9
#define CH 16
#define KTOT 144          // KSZ*CH
#define LSTR 168          // LDS row stride in bf16 elems (pad breaks bank stride, holds zeroed K-pad)
#define NBLK 1792         // 7 blocks/CU x 256 CUs (LDS 22016B -> 7 resident)
#define TILES64 15625     // NN / 64

typedef float f32x4 __attribute__((ext_vector_type(4)));
typedef short s16x8 __attribute__((ext_vector_type(8)));

__device__ __forceinline__ float bf2f(ushort v) { return __uint_as_float(((uint)v) << 16); }
__device__ __forceinline__ ushort f2bf(float f) {
  uint u = __float_as_uint(f);
  return (ushort)((u + 0x7fffu + ((u >> 16) & 1u)) >> 16);   // RNE
}
__device__ __forceinline__ float leaky(float x) { return x >= 0.f ? x : 0.2f * x; }

// One wave owns a 16-node tile IN ITS PRIVATE LDS REGION: gather 144 rows
// (16 nodes x 9 nbrs x 16ch) as bf16, then 5x mfma_16x16x32_bf16 (K=144 pad 160)
// with register-resident weight B-fragments. NO __syncthreads in the loop:
// tiles are wave-private, intra-wave DS ordering is compiler-enforced (lgkmcnt).
// FP32SRC: src rows are fp32 (conv1, + bias). else: bf16 rows, pure copy (conv2).
template<bool FP32SRC>
__global__ __launch_bounds__(256, 7)
void k_conv(const void* __restrict__ srcv, const int* __restrict__ ind,
            const float* __restrict__ w, const float* __restrict__ bias,
            ushort* __restrict__ outv, float* __restrict__ partial) {
  const int lane = threadIdx.x & 63;
  const int wid  = threadIdx.x >> 6;
  const int o = lane & 15;           // B/D column (= out channel)
  const int q = lane >> 4;

  __shared__ ushort lds[4][16 * LSTR];     // 21504 B
  __shared__ float red[4][32];
  ushort* my = lds[wid];

  // zero K-pad [144,160) of each node row once (never rewritten; wave-private)
  {
    int n = lane >> 2, part = lane & 3;
    *(unsigned long long*)&my[n * LSTR + KTOT + part * 4] = 0ULL;
  }

  // B fragments: B[k][o] = w[c*144 + o*9 + j], k = j*16 + c; lane holds k = 32t + 8q + i
  s16x8 bfrag[5];
#pragma unroll
  for (int t = 0; t < 5; ++t) {
#pragma unroll
    for (int i = 0; i < 8; ++i) {
      int k = t * 32 + q * 8 + i;
      ushort wv = 0;
      if (k < KTOT) { int j = k >> 4, c = k & 15; wv = f2bf(w[(c * CH + o) * KSZ + j]); }
      bfrag[t][i] = (short)wv;
    }
  }

  float bo = FP32SRC ? bias[o] : 0.f;
  float wsum = 0.f, wsq = 0.f;

  for (int g = blockIdx.x; g < TILES64; g += NBLK) {
    const int base = g * 64 + wid * 16;

    // prefetch all 3 phases' indices first (MLP)
    int idxv[3];
#pragma unroll
    for (int ph = 0; ph < 3; ++ph) {
      int r = lane + ph * 64;
      int rr = (r < KTOT) ? r : lane;          // inactive lanes: dummy valid index
      int nsub = rr / KSZ;
      int j = rr - nsub * KSZ;
      idxv[ph] = ind[(base + nsub) * KSZ + j];
    }

    // gather rows into wave-private LDS tile
#pragma unroll
    for (int ph = 0; ph < 3; ++ph) {
      int r = lane + ph * 64;
      if (r < KTOT) {
        int nsub = r / KSZ;
        int j = r - nsub * KSZ;
        int idx = idxv[ph];
        uint pk[8];
        if (FP32SRC) {
          const float4* sp = (const float4*)((const float*)srcv + (size_t)idx * CH);
          float4 f0 = sp[0], f1 = sp[1], f2 = sp[2], f3 = sp[3];
          float e[16] = {f0.x,f0.y,f0.z,f0.w, f1.x,f1.y,f1.z,f1.w,
                         f2.x,f2.y,f2.z,f2.w, f3.x,f3.y,f3.z,f3.w};
#pragma unroll
          for (int p = 0; p < 8; ++p)
            pk[p] = (uint)f2bf(e[2*p]) | ((uint)f2bf(e[2*p+1]) << 16);
        } else {
          const uint4* s4 = (const uint4*)((const ushort*)srcv + (size_t)idx * CH);
          uint4 lo = s4[0], hi = s4[1];
          pk[0]=lo.x; pk[1]=lo.y; pk[2]=lo.z; pk[3]=lo.w;
          pk[4]=hi.x; pk[5]=hi.y; pk[6]=hi.z; pk[7]=hi.w;
        }
        uint4* d4 = (uint4*)&my[nsub * LSTR + j * CH];
        d4[0] = *(uint4*)&pk[0];
        d4[1] = *(uint4*)&pk[4];
      }
    }
    // no barrier: wave-private tile, DS ops ordered within wave

    const ushort* ap = &my[o * LSTR + q * 8];   // A[m=o][k]: k = 32t + 8q + i
    f32x4 acc = {0.f, 0.f, 0.f, 0.f};
#pragma unroll
    for (int t = 0; t < 5; ++t) {
      s16x8 a = *(const s16x8*)(ap + t * 32);
      acc = __builtin_amdgcn_mfma_f32_16x16x32_bf16(a, bfrag[t], acc, 0, 0, 0);
    }
    // D[m][o]: m = q*4+r (node within tile), o = lane&15 (channel)
#pragma unroll
    for (int r = 0; r < 4; ++r) {
      float v = acc[r] + bo;
      ushort hv = f2bf(v);
      outv[(size_t)(base + q * 4 + r) * CH + o] = hv;
      float vr = bf2f(hv);     // stats on the ROUNDED value (matches stored tensor)
      wsum += vr;
      wsq  += vr * vr;
    }
  }

  // per-channel reduce: lanes o, o+16, o+32, o+48
  wsum += __shfl_xor(wsum, 16);  wsum += __shfl_xor(wsum, 32);
  wsq  += __shfl_xor(wsq, 16);   wsq  += __shfl_xor(wsq, 32);
  if (lane < 16) { red[wid][lane] = wsum; red[wid][16 + lane] = wsq; }
  __syncthreads();
  if (threadIdx.x < 32) {
    float s = red[0][threadIdx.x] + red[1][threadIdx.x] + red[2][threadIdx.x] + red[3][threadIdx.x];
    partial[blockIdx.x * 32 + threadIdx.x] = s;  // [0..15]=sum, [16..31]=sumsq
  }
}

__global__ __launch_bounds__(256)
void k_finalize(const float* __restrict__ partial, const float* __restrict__ gamma,
                const float* __restrict__ beta, float* __restrict__ derived) {
  __shared__ float red[8][32];
  __shared__ float tot[32];
  int t = threadIdx.x, ch = t & 31, seg = t >> 5;
  const int PER = NBLK / 8;   // 224
  float s = 0.f;
  for (int i = 0; i < PER; ++i) s += partial[(seg * PER + i) * 32 + ch];
  red[seg][ch] = s;
  __syncthreads();
  if (t < 32) {
    float x = 0.f;
#pragma unroll
    for (int k = 0; k < 8; ++k) x += red[k][t];
    tot[t] = x;
  }
  __syncthreads();
  if (t < 16) {
    float mean = tot[t] * (1.0f / NN);
    float var  = tot[16 + t] * (1.0f / NN) - mean * mean;
    float scale = gamma[t] / sqrtf(var + 1e-5f);
    derived[t] = scale;
    derived[16 + t] = beta[t] - mean * scale;
  }
}

// dense h = bf16(leaky(scale1*x + shift1)), 8 bf16 per thread
__global__ __launch_bounds__(256)
void k_bnleaky(const ushort* __restrict__ in, const float* __restrict__ drv,
               ushort* __restrict__ outp) {
  size_t t = (size_t)blockIdx.x * 256 + threadIdx.x;
  size_t i0 = t * 8;
  if (i0 >= (size_t)NN * CH) return;
  int coff = (int)(i0 & 15);  // 0 or 8
  float4 s0 = *(const float4*)(drv + coff);
  float4 s1 = *(const float4*)(drv + coff + 4);
  float4 h0 = *(const float4*)(drv + 16 + coff);
  float4 h1 = *(const float4*)(drv + 16 + coff + 4);
  float sc[8] = {s0.x,s0.y,s0.z,s0.w,s1.x,s1.y,s1.z,s1.w};
  float sh[8] = {h0.x,h0.y,h0.z,h0.w,h1.x,h1.y,h1.z,h1.w};
  uint4 a = *(const uint4*)(in + i0);
  uint ua[4] = {a.x,a.y,a.z,a.w};
  uint res[4];
#pragma unroll
  for (int p = 0; p < 4; ++p) {
    float x0 = __uint_as_float(ua[p] << 16);
    float x1 = __uint_as_float(ua[p] & 0xffff0000u);
    float y0 = leaky(sc[2*p]   * x0 + sh[2*p]);
    float y1 = leaky(sc[2*p+1] * x1 + sh[2*p+1]);
    res[p] = (uint)f2bf(y0) | ((uint)f2bf(y1) << 16);
  }
  uint4 r4; r4.x=res[0]; r4.y=res[1]; r4.z=res[2]; r4.w=res[3];
  *(uint4*)(outp + i0) = r4;
}

// out = leaky(scale2*out2 + shift2 + data), fp32 out
__global__ __launch_bounds__(256)
void k_final(const ushort* __restrict__ o2, const float* __restrict__ data,
             const float* __restrict__ drv, float* __restrict__ out) {
  size_t t = (size_t)blockIdx.x * 256 + threadIdx.x;
  size_t i0 = t * 8;
  if (i0 >= (size_t)NN * CH) return;
  int coff = (int)(i0 & 15);
  float4 s0 = *(const float4*)(drv + coff);
  float4 s1 = *(const float4*)(drv + coff + 4);
  float4 h0 = *(const float4*)(drv + 16 + coff);
  float4 h1 = *(const float4*)(drv + 16 + coff + 4);
  float sc[8] = {s0.x,s0.y,s0.z,s0.w,s1.x,s1.y,s1.z,s1.w};
  float sh[8] = {h0.x,h0.y,h0.z,h0.w,h1.x,h1.y,h1.z,h1.w};
  uint4 a = *(const uint4*)(o2 + i0);
  float4 d0 = *(const float4*)(data + i0);
  float4 d1 = *(const float4*)(data + i0 + 4);
  uint ua[4] = {a.x,a.y,a.z,a.w};
  float dd[8] = {d0.x,d0.y,d0.z,d0.w, d1.x,d1.y,d1.z,d1.w};
  float y[8];
#pragma unroll
  for (int p = 0; p < 4; ++p) {
    float x0 = __uint_as_float(ua[p] << 16);
    float x1 = __uint_as_float(ua[p] & 0xffff0000u);
    y[2*p]   = leaky(sc[2*p]   * x0 + sh[2*p]   + dd[2*p]);
    y[2*p+1] = leaky(sc[2*p+1] * x1 + sh[2*p+1] + dd[2*p+1]);
  }
  float4 r0 = {y[0], y[1], y[2], y[3]};
  float4 r1 = {y[4], y[5], y[6], y[7]};
  *(float4*)(out + i0) = r0;
  *(float4*)(out + i0 + 4) = r1;
}

extern "C" void kernel_launch(void* const* d_in, const int* in_sizes, int n_in,
                              void* d_out, int out_size, void* d_ws, size_t ws_size,
                              hipStream_t stream) {
  const float* data   = (const float*)d_in[0];
  const int*   ind    = (const int*)d_in[1];
  const float* w1     = (const float*)d_in[2];
  const float* b1     = (const float*)d_in[3];
  const float* gamma1 = (const float*)d_in[4];
  const float* beta1  = (const float*)d_in[5];
  const float* w2     = (const float*)d_in[6];
  const float* gamma2 = (const float*)d_in[7];
  const float* beta2  = (const float*)d_in[8];
  float* out = (float*)d_out;

  // d_out (64MB fp32) doubles as scratch until k_final overwrites:
  //   [0,32MB) = out1_raw bf16 (pre-BN1), [32MB,64MB) = h table bf16 (post BN1+leaky)
  ushort* out1 = (ushort*)d_out;
  ushort* htab = (ushort*)d_out + (size_t)NN * CH;
  // ws: out2 bf16 (32MB) | partial1 | partial2 | derived1 | derived2
  ushort* out2     = (ushort*)d_ws;
  float*  partial1 = (float*)((char*)d_ws + 32000000);
  float*  partial2 = partial1 + NBLK * 32;
  float*  derived1 = partial2 + NBLK * 32;
  float*  derived2 = derived1 + 32;

  const int EBLK = (NN * CH / 8 + 255) / 256;

  // conv1: data (fp32) -> out1 (bf16 pre-BN) + stats partials
  hipLaunchKernelGGL((k_conv<true>), dim3(NBLK), dim3(256), 0, stream,
                     (const void*)data, ind, w1, b1, out1, partial1);
  hipLaunchKernelGGL(k_finalize, dim3(1), dim3(256), 0, stream,
                     partial1, gamma1, beta1, derived1);
  // dense BN1+leaky: out1 -> htab
  hipLaunchKernelGGL(k_bnleaky, dim3(EBLK), dim3(256), 0, stream,
                     out1, derived1, htab);
  // conv2: pure gather from htab -> out2 (bf16 pre-BN) + stats
  hipLaunchKernelGGL((k_conv<false>), dim3(NBLK), dim3(256), 0, stream,
                     (const void*)htab, ind, w2, (const float*)nullptr, out2, partial2);
  hipLaunchKernelGGL(k_finalize, dim3(1), dim3(256), 0, stream,
                     partial2, gamma2, beta2, derived2);
  // residual + BN2 + leaky -> d_out (fp32; scratch regions dead)
  hipLaunchKernelGGL(k_final, dim3(EBLK), dim3(256), 0, stream,
                     out2, data, derived2, out);
}

// Round 4
// 475.037 us; speedup vs baseline: 1.0303x; 1.0303x over previous
//
#include <hip/hip_runtime.h>

typedef unsigned int uint;
typedef unsigned short ushort;

#define NN 1000000
#define KSZ 9
#define CH 16
#define KTOT 144          // KSZ*CH
#define LSTR 168          // LDS row stride in bf16 elems (pad breaks bank stride, holds zeroed K-pad)
#define NBLK 1024
#define TILES64 15625     // NN / 64

typedef float f32x4 __attribute__((ext_vector_type(4)));
typedef short s16x8 __attribute__((ext_vector_type(8)));

__device__ __forceinline__ float bf2f(ushort v) { return __uint_as_float(((uint)v) << 16); }
__device__ __forceinline__ ushort f2bf(float f) {
  uint u = __float_as_uint(f);
  return (ushort)((u + 0x7fffu + ((u >> 16) & 1u)) >> 16);   // RNE
}
__device__ __forceinline__ float leaky(float x) { return x >= 0.f ? x : 0.2f * x; }

// One wave owns a 16-node tile IN ITS PRIVATE LDS REGION: gather 144 rows
// (16 nodes x 9 nbrs x 16ch) as bf16, then 5x mfma_16x16x32_bf16 (K=144 pad 160)
// with register-resident weight B-fragments. No __syncthreads in the loop:
// tiles are wave-private, intra-wave DS ordering is compiler-enforced.
// FP32SRC (conv1): src rows fp32, + bias.
// else    (conv2): src rows bf16 (out1 raw), apply BN1+leaky during gather.
// Gather path is TCP outstanding-miss bound (~3.3 TB/s fill): occupancy and
// inline VALU work in the gather are both proven free (R2/R3 A/B).
template<bool FP32SRC>
__global__ __launch_bounds__(256)
void k_conv(const void* __restrict__ srcv, const int* __restrict__ ind,
            const float* __restrict__ w, const float* __restrict__ bias,
            const float* __restrict__ derived, ushort* __restrict__ outv,
            float* __restrict__ partial) {
  const int lane = threadIdx.x & 63;
  const int wid  = threadIdx.x >> 6;
  const int o = lane & 15;           // B/D column (= out channel)
  const int q = lane >> 4;

  __shared__ ushort lds[4][16 * LSTR];     // 21504 B
  __shared__ float red[4][32];
  ushort* my = lds[wid];

  // zero K-pad [144,160) of each node row once (never rewritten; wave-private)
  {
    int n = lane >> 2, part = lane & 3;
    *(unsigned long long*)&my[n * LSTR + KTOT + part * 4] = 0ULL;
  }

  // B fragments: B[k][o] = w[c*144 + o*9 + j], k = j*16 + c; lane holds k = 32t + 8q + i
  s16x8 bfrag[5];
#pragma unroll
  for (int t = 0; t < 5; ++t) {
#pragma unroll
    for (int i = 0; i < 8; ++i) {
      int k = t * 32 + q * 8 + i;
      ushort wv = 0;
      if (k < KTOT) { int j = k >> 4, c = k & 15; wv = f2bf(w[(c * CH + o) * KSZ + j]); }
      bfrag[t][i] = (short)wv;
    }
  }

  float bo = FP32SRC ? bias[o] : 0.f;

  float sc[16], sh[16];
  if (!FP32SRC) {
#pragma unroll
    for (int b = 0; b < 4; ++b) {
      float4 v = *(const float4*)(derived + b * 4);
      sc[b*4+0]=v.x; sc[b*4+1]=v.y; sc[b*4+2]=v.z; sc[b*4+3]=v.w;
      float4 u = *(const float4*)(derived + 16 + b * 4);
      sh[b*4+0]=u.x; sh[b*4+1]=u.y; sh[b*4+2]=u.z; sh[b*4+3]=u.w;
    }
  }

  float wsum = 0.f, wsq = 0.f;

  for (int g = blockIdx.x; g < TILES64; g += NBLK) {
    const int base = g * 64 + wid * 16;

    // prefetch all 3 phases' indices first
    int idxv[3];
#pragma unroll
    for (int ph = 0; ph < 3; ++ph) {
      int r = lane + ph * 64;
      int rr = (r < KTOT) ? r : lane;          // inactive lanes: dummy valid index
      int nsub = rr / KSZ;
      int j = rr - nsub * KSZ;
      idxv[ph] = ind[(base + nsub) * KSZ + j];
    }

    // gather rows into wave-private LDS tile
#pragma unroll
    for (int ph = 0; ph < 3; ++ph) {
      int r = lane + ph * 64;
      if (r < KTOT) {
        int nsub = r / KSZ;
        int j = r - nsub * KSZ;
        int idx = idxv[ph];
        uint pk[8];
        if (FP32SRC) {
          const float4* sp = (const float4*)((const float*)srcv + (size_t)idx * CH);
          float4 f0 = sp[0], f1 = sp[1], f2 = sp[2], f3 = sp[3];
          float e[16] = {f0.x,f0.y,f0.z,f0.w, f1.x,f1.y,f1.z,f1.w,
                         f2.x,f2.y,f2.z,f2.w, f3.x,f3.y,f3.z,f3.w};
#pragma unroll
          for (int p = 0; p < 8; ++p)
            pk[p] = (uint)f2bf(e[2*p]) | ((uint)f2bf(e[2*p+1]) << 16);
        } else {
          const uint4* s4 = (const uint4*)((const ushort*)srcv + (size_t)idx * CH);
          uint4 lo = s4[0], hi = s4[1];
          uint uu[8] = {lo.x, lo.y, lo.z, lo.w, hi.x, hi.y, hi.z, hi.w};
#pragma unroll
          for (int p = 0; p < 8; ++p) {   // h = leaky(scale1*x + shift1), back to bf16
            float e0 = __uint_as_float(uu[p] << 16);
            float e1 = __uint_as_float(uu[p] & 0xffff0000u);
            float x0 = leaky(sc[2*p] * e0 + sh[2*p]);
            float x1 = leaky(sc[2*p+1] * e1 + sh[2*p+1]);
            pk[p] = (uint)f2bf(x0) | ((uint)f2bf(x1) << 16);
          }
        }
        uint4* d4 = (uint4*)&my[nsub * LSTR + j * CH];
        d4[0] = *(uint4*)&pk[0];
        d4[1] = *(uint4*)&pk[4];
      }
    }
    // no barrier: wave-private tile, DS ops ordered within wave

    const ushort* ap = &my[o * LSTR + q * 8];   // A[m=o][k]: k = 32t + 8q + i
    f32x4 acc = {0.f, 0.f, 0.f, 0.f};
#pragma unroll
    for (int t = 0; t < 5; ++t) {
      s16x8 a = *(const s16x8*)(ap + t * 32);
      acc = __builtin_amdgcn_mfma_f32_16x16x32_bf16(a, bfrag[t], acc, 0, 0, 0);
    }
    // D[m][o]: m = q*4+r (node within tile), o = lane&15 (channel)
#pragma unroll
    for (int r = 0; r < 4; ++r) {
      float v = acc[r] + bo;
      ushort hv = f2bf(v);
      outv[(size_t)(base + q * 4 + r) * CH + o] = hv;
      float vr = bf2f(hv);     // stats on the ROUNDED value (matches stored tensor)
      wsum += vr;
      wsq  += vr * vr;
    }
  }

  // per-channel reduce: lanes o, o+16, o+32, o+48
  wsum += __shfl_xor(wsum, 16);  wsum += __shfl_xor(wsum, 32);
  wsq  += __shfl_xor(wsq, 16);   wsq  += __shfl_xor(wsq, 32);
  if (lane < 16) { red[wid][lane] = wsum; red[wid][16 + lane] = wsq; }
  __syncthreads();
  if (threadIdx.x < 32) {
    float s = red[0][threadIdx.x] + red[1][threadIdx.x] + red[2][threadIdx.x] + red[3][threadIdx.x];
    partial[blockIdx.x * 32 + threadIdx.x] = s;  // [0..15]=sum, [16..31]=sumsq
  }
}

// 1024 threads: 32 channels x 32 segments, 32 independent loads each (~3us)
__global__ __launch_bounds__(1024)
void k_finalize(const float* __restrict__ partial, const float* __restrict__ gamma,
                const float* __restrict__ beta, float* __restrict__ derived) {
  __shared__ float red[32][33];
  __shared__ float tot[32];
  int t = threadIdx.x, ch = t & 31, seg = t >> 5;   // seg in [0,32)
  float s = 0.f;
#pragma unroll
  for (int i = 0; i < 32; i += 8) {
    float a0 = partial[(seg * 32 + i + 0) * 32 + ch];
    float a1 = partial[(seg * 32 + i + 1) * 32 + ch];
    float a2 = partial[(seg * 32 + i + 2) * 32 + ch];
    float a3 = partial[(seg * 32 + i + 3) * 32 + ch];
    float a4 = partial[(seg * 32 + i + 4) * 32 + ch];
    float a5 = partial[(seg * 32 + i + 5) * 32 + ch];
    float a6 = partial[(seg * 32 + i + 6) * 32 + ch];
    float a7 = partial[(seg * 32 + i + 7) * 32 + ch];
    s += ((a0 + a1) + (a2 + a3)) + ((a4 + a5) + (a6 + a7));
  }
  red[seg][ch] = s;
  __syncthreads();
  if (t < 32) {
    float x = 0.f;
#pragma unroll
    for (int k = 0; k < 32; ++k) x += red[k][t];
    tot[t] = x;
  }
  __syncthreads();
  if (t < 16) {
    float mean = tot[t] * (1.0f / NN);
    float var  = tot[16 + t] * (1.0f / NN) - mean * mean;
    float scale = gamma[t] / sqrtf(var + 1e-5f);
    derived[t] = scale;
    derived[16 + t] = beta[t] - mean * scale;
  }
}

// out = leaky(scale2*out2 + shift2 + data), fp32 out
__global__ __launch_bounds__(256)
void k_final(const ushort* __restrict__ o2, const float* __restrict__ data,
             const float* __restrict__ drv, float* __restrict__ out) {
  size_t t = (size_t)blockIdx.x * 256 + threadIdx.x;
  size_t i0 = t * 8;
  if (i0 >= (size_t)NN * CH) return;
  int coff = (int)(i0 & 15);
  float4 s0 = *(const float4*)(drv + coff);
  float4 s1 = *(const float4*)(drv + coff + 4);
  float4 h0 = *(const float4*)(drv + 16 + coff);
  float4 h1 = *(const float4*)(drv + 16 + coff + 4);
  float sc[8] = {s0.x,s0.y,s0.z,s0.w,s1.x,s1.y,s1.z,s1.w};
  float sh[8] = {h0.x,h0.y,h0.z,h0.w,h1.x,h1.y,h1.z,h1.w};
  uint4 a = *(const uint4*)(o2 + i0);
  float4 d0 = *(const float4*)(data + i0);
  float4 d1 = *(const float4*)(data + i0 + 4);
  uint ua[4] = {a.x,a.y,a.z,a.w};
  float dd[8] = {d0.x,d0.y,d0.z,d0.w, d1.x,d1.y,d1.z,d1.w};
  float y[8];
#pragma unroll
  for (int p = 0; p < 4; ++p) {
    float x0 = __uint_as_float(ua[p] << 16);
    float x1 = __uint_as_float(ua[p] & 0xffff0000u);
    y[2*p]   = leaky(sc[2*p]   * x0 + sh[2*p]   + dd[2*p]);
    y[2*p+1] = leaky(sc[2*p+1] * x1 + sh[2*p+1] + dd[2*p+1]);
  }
  float4 r0 = {y[0], y[1], y[2], y[3]};
  float4 r1 = {y[4], y[5], y[6], y[7]};
  *(float4*)(out + i0) = r0;
  *(float4*)(out + i0 + 4) = r1;
}

extern "C" void kernel_launch(void* const* d_in, const int* in_sizes, int n_in,
                              void* d_out, int out_size, void* d_ws, size_t ws_size,
                              hipStream_t stream) {
  const float* data   = (const float*)d_in[0];
  const int*   ind    = (const int*)d_in[1];
  const float* w1     = (const float*)d_in[2];
  const float* b1     = (const float*)d_in[3];
  const float* gamma1 = (const float*)d_in[4];
  const float* beta1  = (const float*)d_in[5];
  const float* w2     = (const float*)d_in[6];
  const float* gamma2 = (const float*)d_in[7];
  const float* beta2  = (const float*)d_in[8];
  float* out = (float*)d_out;

  // d_out (64MB fp32) doubles as scratch until k_final overwrites:
  //   [0,32MB) = out1 bf16 (pre-BN1 raw; conv2 applies BN1+leaky during gather)
  ushort* out1 = (ushort*)d_out;
  // ws: out2 bf16 (32MB) | partial1 | partial2 | derived1 | derived2
  ushort* out2     = (ushort*)d_ws;
  float*  partial1 = (float*)((char*)d_ws + 32000000);
  float*  partial2 = partial1 + NBLK * 32;
  float*  derived1 = partial2 + NBLK * 32;
  float*  derived2 = derived1 + 32;

  // conv1: data (fp32) -> out1 (bf16 pre-BN) + stats partials
  hipLaunchKernelGGL((k_conv<true>), dim3(NBLK), dim3(256), 0, stream,
                     (const void*)data, ind, w1, b1, (const float*)nullptr, out1, partial1);
  hipLaunchKernelGGL(k_finalize, dim3(1), dim3(1024), 0, stream,
                     partial1, gamma1, beta1, derived1);
  // conv2: gather out1, BN1+leaky inline -> out2 (bf16 pre-BN) + stats
  hipLaunchKernelGGL((k_conv<false>), dim3(NBLK), dim3(256), 0, stream,
                     (const void*)out1, ind, w2, (const float*)nullptr, derived1, out2, partial2);
  hipLaunchKernelGGL(k_finalize, dim3(1), dim3(1024), 0, stream,
                     partial2, gamma2, beta2, derived2);
  // residual + BN2 + leaky -> d_out (fp32; scratch region dead)
  hipLaunchKernelGGL(k_final, dim3((NN * CH / 8 + 255) / 256), dim3(256), 0, stream,
                     out2, data, derived2, out);
}